// Round 1
// baseline (883.479 us; speedup 1.0000x reference)
//
#include <hip/hip_runtime.h>
#include <hip/hip_bf16.h>

// RelationalKENN: u = unary + unary-clause softmax deltas (per-node),
// then per-edge 3-way softmaxes over (u[i1][c], binary[e][c], u[i2][c]) for
// c in 0..3, scatter-add into up, bp = binary + db.
//
// Layout: d_out = [ up : n_nodes*16 fp32 | bp : n_edges*4 fp32 ]
// d_ws   = clean copy of u (n_nodes*16 fp32) so the edge kernel's gathers
//          never race with the atomics into d_out's up region.

__device__ __forceinline__ void sm2(float xi, float xj, float w,
                                    float& di, float& dj) {
    // idx [i,j], sgn [-1,+1]: sel = [-xi, xj]
    float na = -xi, b = xj;
    float m  = fmaxf(na, b);
    float e0 = __expf(na - m), e1 = __expf(b - m);
    float inv = w / (e0 + e1);
    di -= e0 * inv;
    dj += e1 * inv;
}

__device__ __forceinline__ void sm3(float xi, float xj, float xk, float w,
                                    float& di, float& dj, float& dk) {
    // idx [i,j,k], sgn [-1,+1,+1]: sel = [-xi, xj, xk]
    float na = -xi, b = xj, c = xk;
    float m  = fmaxf(fmaxf(na, b), c);
    float e0 = __expf(na - m), e1 = __expf(b - m), e2 = __expf(c - m);
    float inv = w / (e0 + e1 + e2);
    di -= e0 * inv;
    dj += e1 * inv;
    dk += e2 * inv;
}

__global__ void unary_kernel(const float* __restrict__ x_in,
                             const float* __restrict__ uw,
                             float* __restrict__ u_ws,   // clean u copy
                             float* __restrict__ up,     // d_out up region
                             int n_nodes) {
    int n = blockIdx.x * blockDim.x + threadIdx.x;
    if (n >= n_nodes) return;

    const float4* xr = (const float4*)(x_in + (size_t)n * 16);
    float4 r0 = xr[0], r1 = xr[1], r2 = xr[2], r3 = xr[3];
    float x[16] = {r0.x, r0.y, r0.z, r0.w,
                   r1.x, r1.y, r1.z, r1.w,
                   r2.x, r2.y, r2.z, r2.w,
                   r3.x, r3.y, r3.z, r3.w};
    float d[16];
#pragma unroll
    for (int i = 0; i < 16; ++i) d[i] = 0.0f;

    // UNARY_CLAUSES
    sm2(x[0],  x[1],          uw[0], d[0],  d[1]);
    sm2(x[1],  x[2],          uw[1], d[1],  d[2]);
    sm3(x[2],  x[3],  x[4],   uw[2], d[2],  d[3],  d[4]);
    sm2(x[4],  x[5],          uw[3], d[4],  d[5]);
    sm3(x[6],  x[7],  x[8],   uw[4], d[6],  d[7],  d[8]);
    sm2(x[8],  x[9],          uw[5], d[8],  d[9]);
    sm3(x[10], x[11], x[12],  uw[6], d[10], d[11], d[12]);
    sm3(x[13], x[14], x[15],  uw[7], d[13], d[14], d[15]);

    float u[16];
#pragma unroll
    for (int i = 0; i < 16; ++i) u[i] = x[i] + d[i];

    float4* w_ws = (float4*)(u_ws + (size_t)n * 16);
    float4* w_up = (float4*)(up   + (size_t)n * 16);
#pragma unroll
    for (int i = 0; i < 4; ++i) {
        float4 v = make_float4(u[4*i], u[4*i+1], u[4*i+2], u[4*i+3]);
        w_ws[i] = v;
        w_up[i] = v;
    }
}

__global__ void edge_kernel(const float* __restrict__ u,      // clean copy (ws)
                            const float4* __restrict__ binary,
                            const int* __restrict__ idx1,
                            const int* __restrict__ idx2,
                            const float* __restrict__ bw,
                            float* __restrict__ up,            // accumulate
                            float4* __restrict__ bp,
                            int n_edges) {
    int e = blockIdx.x * blockDim.x + threadIdx.x;
    if (e >= n_edges) return;

    int n1 = idx1[e];
    int n2 = idx2[e];
    float4 b4 = binary[e];
    float4 a4 = *(const float4*)(u + (size_t)n1 * 16);  // u[n1][0..3]
    float4 c4 = *(const float4*)(u + (size_t)n2 * 16);  // u[n2][0..3]

    float a[4]  = {a4.x, a4.y, a4.z, a4.w};
    float bb[4] = {b4.x, b4.y, b4.z, b4.w};
    float c[4]  = {c4.x, c4.y, c4.z, c4.w};
    float w[4]  = {bw[0], bw[1], bw[2], bw[3]};

    float* up1 = up + (size_t)n1 * 16;
    float* up2 = up + (size_t)n2 * 16;
    float dbv[4];

#pragma unroll
    for (int i = 0; i < 4; ++i) {
        // clause ([i, 32+i, 16+i], [-1,-1,+1]) on joined = [u1 | u2 | binary]:
        // sel = [-u1_i, -b_i, u2_i]
        float na = -a[i], nb = -bb[i], cc = c[i];
        float m  = fmaxf(fmaxf(na, nb), cc);
        float e0 = __expf(na - m), e1 = __expf(nb - m), e2 = __expf(cc - m);
        float inv = w[i] / (e0 + e1 + e2);
        atomicAdd(up1 + i, -e0 * inv);   // du1
        atomicAdd(up2 + i,  e2 * inv);   // du2
        dbv[i] = bb[i] - e1 * inv;       // bp = binary + db
    }

    bp[e] = make_float4(dbv[0], dbv[1], dbv[2], dbv[3]);
}

extern "C" void kernel_launch(void* const* d_in, const int* in_sizes, int n_in,
                              void* d_out, int out_size, void* d_ws, size_t ws_size,
                              hipStream_t stream) {
    const float* unary   = (const float*)d_in[0];
    const float* binary  = (const float*)d_in[1];
    const int*   index1  = (const int*)d_in[2];
    const int*   index2  = (const int*)d_in[3];
    const float* uw      = (const float*)d_in[4];
    const float* bw      = (const float*)d_in[5];

    int n_nodes = in_sizes[0] / 16;
    int n_edges = in_sizes[2];

    float* out = (float*)d_out;
    float* up  = out;                                // n_nodes*16
    float* bp  = out + (size_t)n_nodes * 16;         // n_edges*4
    float* u_ws = (float*)d_ws;                      // n_nodes*16 clean u

    unary_kernel<<<(n_nodes + 255) / 256, 256, 0, stream>>>(
        unary, uw, u_ws, up, n_nodes);
    edge_kernel<<<(n_edges + 255) / 256, 256, 0, stream>>>(
        u_ws, (const float4*)binary, index1, index2, bw,
        up, (float4*)bp, n_edges);
}